// Round 12
// baseline (259.588 us; speedup 1.0000x reference)
//
#include <hip/hip_runtime.h>
#include <cstdint>
#include <cstddef>

#define DM   1024
#define HEADS 16
#define DH    64
#define SEQL  2048
#define BATCH 2
#define MTOT  (BATCH*SEQL)   // 4096
#define BK    32             // qkv k-step (R12: halved for dbuf occupancy)

typedef __attribute__((ext_vector_type(8))) short short8;
typedef __attribute__((ext_vector_type(4))) float floatx4;

__device__ __forceinline__ unsigned short f2bf(float f) {
  unsigned int u = __float_as_uint(f);
  u = (u + 0x7FFFu + ((u >> 16) & 1u)) >> 16;   // RNE
  return (unsigned short)u;
}

__device__ __forceinline__ float exp2_fast(float x) {
#if __has_builtin(__builtin_amdgcn_exp2f)
  return __builtin_amdgcn_exp2f(x);      // single v_exp_f32
#else
  return exp2f(x);
#endif
}

__device__ __forceinline__ unsigned int cvt_pk_bf16(float lo, float hi) {
  unsigned int r;
  asm("v_cvt_pk_bf16_f32 %0, %1, %2" : "=v"(r) : "v"(lo), "v"(hi));
  return r;
}

__device__ __forceinline__ void async_ld16(const void* g, void* l) {
  __builtin_amdgcn_global_load_lds(
      (const __attribute__((address_space(1))) unsigned int*)g,
      (__attribute__((address_space(3))) unsigned int*)l, 16, 0, 0);
}

// 1/sqrt(64) * log2(e) — folded into Q at qkv_gemm epilogue
#define QSCALE 0.1803368801111204f

// ---------------- fp32->bf16 convert (4 weight tensors only; X fused into qkv) ----------------
__global__ void cvt_w(const float* __restrict__ w0, const float* __restrict__ w1,
                      const float* __restrict__ w2, const float* __restrict__ w3,
                      unsigned short* __restrict__ W0, unsigned short* __restrict__ W1,
                      unsigned short* __restrict__ W2, unsigned short* __restrict__ W3) {
  const int bid = blockIdx.x;
  const int seg = bid >> 10;
  const int base = (bid & 1023) * 1024;
  const float* src = seg == 0 ? w0 : seg == 1 ? w1 : seg == 2 ? w2 : w3;
  unsigned short* dst = seg == 0 ? W0 : seg == 1 ? W1 : seg == 2 ? W2 : W3;
  int i = base + threadIdx.x * 4;
  float4 vv = *(const float4*)(src + i);
  ushort4 o;
  o.x = f2bf(vv.x); o.y = f2bf(vv.y); o.z = f2bf(vv.z); o.w = f2bf(vv.w);
  *(ushort4*)(dst + i) = o;
}

// ---------------- qkv GEMM: 128x128 tile, C = bf16(A_f32) @ B^T + bias ----------------
// R12: XCD-panel swizzle PROVEN (R11: FETCH 200->49MB). Remaining stall is the
// serial stage chain (R11: 69µs, MfmaUtil 14%, HBM 13%). Fix: BK=32 + full LDS
// double-buffer (32KB -> 5 blocks/CU, 20 waves/CU) + T14 ordering: A-loads(kt+1)
// + B-DMA(kt+1) issued BEFORE compute(kt); cvt+ds_write AFTER; 1 barrier/step.
// fr[4] = 16 VGPR live across MFMAs (R9's spill was 64 — this fits, ~110 total).
// z==0 output scaled by QSCALE; z==2 writes VT layout [b][h][kt64][d][k].
__global__ __launch_bounds__(256, 5) void qkv_gemm(
    const float* __restrict__ Xq, const float* __restrict__ Xk, const float* __restrict__ Xv,
    const unsigned short* __restrict__ Wq, const unsigned short* __restrict__ Wk,
    const unsigned short* __restrict__ Wv,
    const float* __restrict__ bq, const float* __restrict__ bk, const float* __restrict__ bv,
    unsigned short* Qo, unsigned short* Ko, unsigned short* VTo) {
  __shared__ unsigned short As[2][128 * BK], Bs[2][128 * BK];

  // XCD-panel swizzle: panel = (bid&7) + 8*(bid>>6); n-block = (bid>>3)&7.
  const int bid  = blockIdx.x;
  const int xcd  = bid & 7;
  const int idx  = bid >> 3;
  const int pgrp = idx >> 3;
  const int nblk = idx & 7;
  const int panel = xcd + 8 * pgrp;       // 0..95
  const int mblk = panel & 31;
  const int z    = panel >> 5;            // 0..2

  const float* A; const unsigned short* Bw; const float* bias; unsigned short* Cout;
  if (z == 0)      { A = Xq; Bw = Wq; bias = bq; Cout = Qo; }
  else if (z == 1) { A = Xk; Bw = Wk; bias = bk; Cout = Ko; }
  else             { A = Xv; Bw = Wv; bias = bv; Cout = VTo; }

  const int K = DM, N = DM;
  const int m0 = mblk * 128, n0 = nblk * 128;
  const int tid  = threadIdx.x;
  const int lane = tid & 63, wvi = tid >> 6;
  const int lq = lane & 15, quad = lane >> 4;
  const int wrow = wvi >> 1, wcol = wvi & 1;

  floatx4 acc[4][4];
  #pragma unroll
  for (int i = 0; i < 4; i++)
    #pragma unroll
    for (int j = 0; j < 4; j++)
      #pragma unroll
      for (int e = 0; e < 4; e++) acc[i][j][e] = 0.0f;

  // staging addressing: chunk c in 0..7 covers 512 elems (16 rows x 32 cols);
  // e = c*512 + lane*8 -> r = e>>5, col = e&31 (8 elems/lane)
  auto stageB = [&](int buf, int kt) {
    #pragma unroll
    for (int cc = 0; cc < 2; cc++) {
      int c = wvi + cc * 4;
      int e = c * 512 + lane * 8;
      int r = e >> 5, col = e & 31;
      async_ld16(Bw + (size_t)(n0 + r) * K + kt + col, &Bs[buf][c * 512 + lane * 8]);
    }
  };
  auto loadA = [&](float4 (&f)[4], int kt) {
    #pragma unroll
    for (int cc = 0; cc < 2; cc++) {
      int c = wvi + cc * 4;
      int e = c * 512 + lane * 8;
      int r = e >> 5, col = e & 31;
      const float* src = A + (size_t)(m0 + r) * K + kt + col;
      f[cc * 2]     = *(const float4*)(src);
      f[cc * 2 + 1] = *(const float4*)(src + 4);
    }
  };
  auto writeA = [&](int buf, const float4 (&f)[4]) {
    #pragma unroll
    for (int cc = 0; cc < 2; cc++) {
      int c = wvi + cc * 4;
      uint4 w;
      w.x = cvt_pk_bf16(f[cc * 2].x,     f[cc * 2].y);
      w.y = cvt_pk_bf16(f[cc * 2].z,     f[cc * 2].w);
      w.z = cvt_pk_bf16(f[cc * 2 + 1].x, f[cc * 2 + 1].y);
      w.w = cvt_pk_bf16(f[cc * 2 + 1].z, f[cc * 2 + 1].w);
      *(uint4*)(&As[buf][c * 512 + lane * 8]) = w;
    }
  };
  auto compute = [&](int buf) {
    short8 af[4], bf[4];
    #pragma unroll
    for (int i = 0; i < 4; i++)
      af[i] = *(const short8*)&As[buf][(wrow * 64 + i * 16 + lq) * BK + quad * 8];
    #pragma unroll
    for (int j = 0; j < 4; j++)
      bf[j] = *(const short8*)&Bs[buf][(wcol * 64 + j * 16 + lq) * BK + quad * 8];
    #pragma unroll
    for (int i = 0; i < 4; i++)
      #pragma unroll
      for (int j = 0; j < 4; j++)
        acc[i][j] = __builtin_amdgcn_mfma_f32_16x16x32_bf16(af[i], bf[j], acc[i][j], 0, 0, 0);
  };

  const int NKT = K / BK;                 // 32
  float4 fr[4];

  // prologue: stage k-step 0 into buffer 0
  loadA(fr, 0);
  stageB(0, 0);
  writeA(0, fr);
  __syncthreads();

  for (int kt = 0; kt < NKT; kt++) {
    const int cur = kt & 1, nxt = cur ^ 1;
    const int kn = (kt + 1) * BK;
    if (kt + 1 < NKT) {
      loadA(fr, kn);                      // issue early (T14)
      stageB(nxt, kn);                    // async DMA into other buffer
    }
    compute(cur);                         // 8 ds_reads + 16 MFMAs
    if (kt + 1 < NKT) writeA(nxt, fr);    // write late, after MFMAs
    __syncthreads();
  }

  if (z == 2) {
    #pragma unroll
    for (int i = 0; i < 4; i++) {
      const int rowg = m0 + wrow * 64 + i * 16 + quad * 4;   // +r
      const int bb  = rowg >> 11;
      const int kt2 = (rowg & 2047) >> 6;
      const int k0  = rowg & 63;
      #pragma unroll
      for (int j = 0; j < 4; j++) {
        const int colg = n0 + wcol * 64 + j * 16 + lq;
        const int h2 = colg >> 6, d2 = colg & 63;
        const float bb_v = bias[colg];
        ushort4 w;
        w.x = f2bf(acc[i][j][0] + bb_v);
        w.y = f2bf(acc[i][j][1] + bb_v);
        w.z = f2bf(acc[i][j][2] + bb_v);
        w.w = f2bf(acc[i][j][3] + bb_v);
        *(ushort4*)(Cout + (size_t)((bb * HEADS + h2) * 32 + kt2) * 4096 + d2 * 64 + k0) = w;
      }
    }
  } else {
    const float oscale = (z == 0) ? QSCALE : 1.0f;
    #pragma unroll
    for (int i = 0; i < 4; i++) {
      #pragma unroll
      for (int j = 0; j < 4; j++) {
        int colg = n0 + wcol * 64 + j * 16 + lq;
        float bb = bias[colg];
        #pragma unroll
        for (int r = 0; r < 4; r++) {
          int rowg = m0 + wrow * 64 + i * 16 + quad * 4 + r;
          Cout[(size_t)rowg * N + colg] = f2bf((acc[i][j][r] + bb) * oscale);
        }
      }
    }
  }
}

// ---------------- out GEMM: 64x128 tile, fp32 out, grid (8,64) ----------------
__global__ __launch_bounds__(256, 4) void out_gemm(
    const unsigned short* __restrict__ A, const unsigned short* __restrict__ Bw,
    const float* __restrict__ bias, float* __restrict__ C) {
  __shared__ unsigned short As[64 * 64], Bs[128 * 64];
  const int K = DM, N = DM;
  const int m0 = blockIdx.y * 64, n0 = blockIdx.x * 128;
  const int tid  = threadIdx.x;
  const int lane = tid & 63, wvi = tid >> 6;
  const int lq = lane & 15, quad = lane >> 4;

  floatx4 acc[8];
  #pragma unroll
  for (int j = 0; j < 8; j++)
    #pragma unroll
    for (int e = 0; e < 4; e++) acc[j][e] = 0.0f;

  for (int kt = 0; kt < K; kt += 64) {
    #pragma unroll
    for (int cc = 0; cc < 2; cc++) {           // A: 8 chunks of 512
      int c = wvi + cc * 4;
      int e = c * 512 + lane * 8;
      int r = e >> 6, col = e & 63;
      async_ld16(A + (size_t)(m0 + r) * K + kt + col, As + c * 512);
    }
    #pragma unroll
    for (int cc = 0; cc < 4; cc++) {           // B: 16 chunks of 512
      int c = wvi + cc * 4;
      int e = c * 512 + lane * 8;
      int r = e >> 6, col = e & 63;
      async_ld16(Bw + (size_t)(n0 + r) * K + kt + col, Bs + c * 512);
    }
    __syncthreads();
    #pragma unroll
    for (int ks = 0; ks < 64; ks += 32) {
      const short8 af = *(const short8*)&As[(wvi * 16 + lq) * 64 + ks + quad * 8];
      #pragma unroll
      for (int j = 0; j < 8; j++) {
        const short8 bf = *(const short8*)&Bs[(j * 16 + lq) * 64 + ks + quad * 8];
        acc[j] = __builtin_amdgcn_mfma_f32_16x16x32_bf16(af, bf, acc[j], 0, 0, 0);
      }
    }
    __syncthreads();
  }

  #pragma unroll
  for (int j = 0; j < 8; j++) {
    const int colg = n0 + j * 16 + lq;
    const float bb = bias[colg];
    #pragma unroll
    for (int r = 0; r < 4; r++) {
      const int rowg = m0 + wvi * 16 + quad * 4 + r;
      C[(size_t)rowg * N + colg] = acc[j][r] + bb;
    }
  }
}

// ---------------- flash attention (R7 frozen: R2 structure + setprio) ----------------
__global__ __launch_bounds__(256, 4) void attn_kernel(
    const unsigned short* __restrict__ Q, const unsigned short* __restrict__ K,
    const unsigned short* __restrict__ VT, const unsigned char* __restrict__ kpm,
    unsigned short* __restrict__ O) {
  __shared__ unsigned short Ks[64 * 72];
  __shared__ unsigned short VTs[64 * 72];
  __shared__ unsigned short Ps[4][16 * 72];

  const int bid = blockIdx.x;
  const int qt = 31 - (bid >> 5);        // longest q-tiles first
  const int bh = bid & 31;
  const int h = bh & 15, b = bh >> 4;
  const int tid = threadIdx.x, lane = tid & 63, wvi = tid >> 6;
  const int lq = lane & 15, quad = lane >> 4;
  const size_t bbase = (size_t)b * SEQL * DM;

  const int srow = tid >> 4;
  const int scol = (tid & 15) * 4;

  const unsigned short* kptr = K + bbase + (size_t)h * DH + (size_t)srow * DM + scol;
  const unsigned short* vptr = VT + (size_t)(b * HEADS + h) * 32 * 4096 + srow * 64 + scol;
  const unsigned char*  mptr = kpm + (size_t)b * SEQL + quad * 4;

  const unsigned short* Qrow = Q + bbase + (size_t)(qt * 64 + wvi * 16 + lq) * DM + h * DH;
  const short8 qf0 = *(const short8*)(Qrow + quad * 8);
  const short8 qf1 = *(const short8*)(Qrow + 32 + quad * 8);

  ushort4 kr[4], vr[4];
  unsigned int mr[4];
  #pragma unroll
  for (int j = 0; j < 4; j++) {
    kr[j] = *(const ushort4*)(kptr + (size_t)j * 16 * DM);
    vr[j] = *(const ushort4*)(vptr + j * 1024);
  }
  #pragma unroll
  for (int t = 0; t < 4; t++) mr[t] = *(const unsigned int*)(mptr + t * 16);
  kptr += (size_t)64 * DM; vptr += 4096; mptr += 64;

  floatx4 o[4];
  #pragma unroll
  for (int t = 0; t < 4; t++)
    #pragma unroll
    for (int e = 0; e < 4; e++) o[t][e] = 0.f;

  floatx4 lacc;                           // row-sum accumulator via ones-MFMA
  #pragma unroll
  for (int e = 0; e < 4; e++) lacc[e] = 0.f;

  floatx4 zf;                             // hoisted zero C-operand
  #pragma unroll
  for (int e = 0; e < 4; e++) zf[e] = 0.f;

  short8 ones8;                           // bf16 1.0 broadcast (row-sum B)
  #pragma unroll
  for (int e = 0; e < 8; e++) ones8[e] = (short)0x3F80;

  const int qg = wvi * 16 + lq;

  auto tile_body = [&](bool diag, const unsigned int* mcur) {
    floatx4 st[4];
    __builtin_amdgcn_s_setprio(1);
    #pragma unroll
    for (int t = 0; t < 4; t++) {
      const short8 a0 = *(const short8*)&Ks[(t * 16 + lq) * 72 + quad * 8];
      const short8 a1 = *(const short8*)&Ks[(t * 16 + lq) * 72 + 32 + quad * 8];
      st[t] = __builtin_amdgcn_mfma_f32_16x16x32_bf16(a0, qf0, zf, 0, 0, 0);
      st[t] = __builtin_amdgcn_mfma_f32_16x16x32_bf16(a1, qf1, st[t], 0, 0, 0);
    }
    __builtin_amdgcn_s_setprio(0);

    float x[4][4];
    #pragma unroll
    for (int t = 0; t < 4; t++)
      #pragma unroll
      for (int r = 0; r < 4; r++) x[t][r] = st[t][r];

    if (__any((int)((mcur[0] | mcur[1] | mcur[2] | mcur[3]) != 0u))) {   // rare
      #pragma unroll
      for (int t = 0; t < 4; t++)
        #pragma unroll
        for (int r = 0; r < 4; r++)
          if ((mcur[t] >> (8 * r)) & 0xffu) x[t][r] = -1e33f;
    }
    if (diag) {
      #pragma unroll
      for (int t = 0; t < 4; t++)
        #pragma unroll
        for (int r = 0; r < 4; r++)
          if (t * 16 + quad * 4 + r > qg) x[t][r] = -1e33f;
    }

    // p = exp2(S * SC)  — scale pre-folded into Q, C0 cancels in o/l
    #pragma unroll
    for (int t = 0; t < 4; t++)
      #pragma unroll
      for (int r = 0; r < 4; r++)
        x[t][r] = exp2_fast(x[t][r]);

    #pragma unroll
    for (int t = 0; t < 4; t++) {
      unsigned int p01 = cvt_pk_bf16(x[t][0], x[t][1]);
      unsigned int p23 = cvt_pk_bf16(x[t][2], x[t][3]);
      *(uint2*)&Ps[wvi][lq * 72 + t * 16 + quad * 4] = make_uint2(p01, p23);
    }

    const short8 pa0 = *(const short8*)&Ps[wvi][lq * 72 + quad * 8];
    const short8 pa1 = *(const short8*)&Ps[wvi][lq * 72 + 32 + quad * 8];
    __builtin_amdgcn_s_setprio(1);
    #pragma unroll
    for (int t = 0; t < 4; t++) {
      const short8 b0 = *(const short8*)&VTs[(t * 16 + lq) * 72 + quad * 8];
      const short8 b1 = *(const short8*)&VTs[(t * 16 + lq) * 72 + 32 + quad * 8];
      o[t] = __builtin_amdgcn_mfma_f32_16x16x32_bf16(pa0, b0, o[t], 0, 0, 0);
      o[t] = __builtin_amdgcn_mfma_f32_16x16x32_bf16(pa1, b1, o[t], 0, 0, 0);
    }
    // l += P @ ones  (row-sum on the matrix pipe; consistent with bf16 numerator)
    lacc = __builtin_amdgcn_mfma_f32_16x16x32_bf16(pa0, ones8, lacc, 0, 0, 0);
    lacc = __builtin_amdgcn_mfma_f32_16x16x32_bf16(pa1, ones8, lacc, 0, 0, 0);
    __builtin_amdgcn_s_setprio(0);
  };

  for (int kt = 0; kt < qt; kt++) {
    __syncthreads();
    #pragma unroll
    for (int j = 0; j < 4; j++) {
      *(ushort4*)&Ks [(j * 16 + srow) * 72 + scol] = kr[j];
      *(ushort4*)&VTs[(j * 16 + srow) * 72 + scol] = vr[j];
    }
    unsigned int mcur[4];
    #pragma unroll
    for (int t = 0; t < 4; t++) mcur[t] = mr[t];
    __syncthreads();

    #pragma unroll
    for (int j = 0; j < 4; j++) {
      kr[j] = *(const ushort4*)(kptr + (size_t)j * 16 * DM);
      vr[j] = *(const ushort4*)(vptr + j * 1024);
    }
    #pragma unroll
    for (int t = 0; t < 4; t++) mr[t] = *(const unsigned int*)(mptr + t * 16);
    kptr += (size_t)64 * DM; vptr += 4096; mptr += 64;

    tile_body(false, mcur);
  }

  __syncthreads();
  #pragma unroll
  for (int j = 0; j < 4; j++) {
    *(ushort4*)&Ks [(j * 16 + srow) * 72 + scol] = kr[j];
    *(ushort4*)&VTs[(j * 16 + srow) * 72 + scol] = vr[j];
  }
  __syncthreads();
  tile_body(true, mr);

  // lacc[r] holds l for q-row (wvi*16 + quad*4 + r), replicated across lq
  float linv[4];
  #pragma unroll
  for (int r = 0; r < 4; r++) linv[r] = 1.0f / lacc[r];
  #pragma unroll
  for (int t = 0; t < 4; t++)
    #pragma unroll
    for (int r = 0; r < 4; r++) {
      const int rowg = qt * 64 + wvi * 16 + quad * 4 + r;
      const int colg = h * 64 + t * 16 + lq;
      O[bbase + (size_t)rowg * DM + colg] = f2bf(o[t][r] * linv[r]);
    }
}

// ---------------- launch ----------------
extern "C" void kernel_launch(void* const* d_in, const int* in_sizes, int n_in,
                              void* d_out, int out_size, void* d_ws, size_t ws_size,
                              hipStream_t stream) {
  const float* qin = (const float*)d_in[0];
  const float* kin = (const float*)d_in[1];
  const float* vin = (const float*)d_in[2];
  const unsigned char* kpm = (const unsigned char*)d_in[3];
  const float* wq = (const float*)d_in[4];
  const float* bq = (const float*)d_in[5];
  const float* wk = (const float*)d_in[6];
  const float* bk = (const float*)d_in[7];
  const float* wv = (const float*)d_in[8];
  const float* bv = (const float*)d_in[9];
  const float* wo = (const float*)d_in[10];
  const float* bo = (const float*)d_in[11];

  const size_t XN = (size_t)MTOT * DM;   // 4,194,304
  const size_t WN = (size_t)DM * DM;     // 1,048,576
  unsigned short* Wqb = (unsigned short*)d_ws;
  unsigned short* Wkb = Wqb + WN;
  unsigned short* Wvb = Wkb + WN;
  unsigned short* Wob = Wvb + WN;
  unsigned short* Qb  = Wob + WN;
  unsigned short* Kb  = Qb  + XN;
  unsigned short* VTg = Kb  + XN;   // V written directly in VT layout by qkv_gemm
  unsigned short* Ob  = VTg + XN;   // total ~42 MiB

  cvt_w<<<dim3(4096), 256, 0, stream>>>(wq, wk, wv, wo, Wqb, Wkb, Wvb, Wob);

  qkv_gemm<<<dim3(768), 256, 0, stream>>>(qin, kin, vin, Wqb, Wkb, Wvb, bq, bk, bv, Qb, Kb, VTg);

  attn_kernel<<<dim3(BATCH * HEADS * (SEQL / 64)), 256, 0, stream>>>(Qb, Kb, VTg, kpm, Ob);

  dim3 g2(DM / 128, MTOT / 64, 1);
  out_gemm<<<g2, 256, 0, stream>>>(Ob, Wob, bo, (float*)d_out);
}

// Round 13
// 219.512 us; speedup vs baseline: 1.1826x; 1.1826x over previous
//
#include <hip/hip_runtime.h>
#include <cstdint>
#include <cstddef>

#define DM   1024
#define HEADS 16
#define DH    64
#define SEQL  2048
#define BATCH 2
#define MTOT  (BATCH*SEQL)   // 4096

typedef __attribute__((ext_vector_type(8))) short short8;
typedef __attribute__((ext_vector_type(4))) float floatx4;

__device__ __forceinline__ unsigned short f2bf(float f) {
  unsigned int u = __float_as_uint(f);
  u = (u + 0x7FFFu + ((u >> 16) & 1u)) >> 16;   // RNE
  return (unsigned short)u;
}

__device__ __forceinline__ float exp2_fast(float x) {
#if __has_builtin(__builtin_amdgcn_exp2f)
  return __builtin_amdgcn_exp2f(x);      // single v_exp_f32
#else
  return exp2f(x);
#endif
}

__device__ __forceinline__ unsigned int cvt_pk_bf16(float lo, float hi) {
  unsigned int r;
  asm("v_cvt_pk_bf16_f32 %0, %1, %2" : "=v"(r) : "v"(lo), "v"(hi));
  return r;
}

__device__ __forceinline__ void async_ld16(const void* g, void* l) {
  __builtin_amdgcn_global_load_lds(
      (const __attribute__((address_space(1))) unsigned int*)g,
      (__attribute__((address_space(3))) unsigned int*)l, 16, 0, 0);
}

// 1/sqrt(64) * log2(e) — folded into Q at qkv_gemm epilogue
#define QSCALE 0.1803368801111204f

// ---------------- fused fp32->bf16 convert (7 tensors) — R7 restore ----------------
__global__ void cvt_all(const float* __restrict__ q, const float* __restrict__ k,
                        const float* __restrict__ v, const float* __restrict__ w0,
                        const float* __restrict__ w1, const float* __restrict__ w2,
                        const float* __restrict__ w3,
                        unsigned short* __restrict__ Xq, unsigned short* __restrict__ Xk,
                        unsigned short* __restrict__ Xv, unsigned short* __restrict__ W0,
                        unsigned short* __restrict__ W1, unsigned short* __restrict__ W2,
                        unsigned short* __restrict__ W3) {
  const int bid = blockIdx.x;
  const float* src; unsigned short* dst; int base;
  if (bid < 12288) {
    int seg = bid >> 12;
    base = (bid & 4095) * 1024;
    src = seg == 0 ? q : seg == 1 ? k : v;
    dst = seg == 0 ? Xq : seg == 1 ? Xk : Xv;
  } else {
    int b2 = bid - 12288;
    int seg = b2 >> 10;
    base = (b2 & 1023) * 1024;
    src = seg == 0 ? w0 : seg == 1 ? w1 : seg == 2 ? w2 : w3;
    dst = seg == 0 ? W0 : seg == 1 ? W1 : seg == 2 ? W2 : W3;
  }
  int i = base + threadIdx.x * 4;
  float4 vv = *(const float4*)(src + i);
  ushort4 o;
  o.x = f2bf(vv.x); o.y = f2bf(vv.y); o.z = f2bf(vv.z); o.w = f2bf(vv.w);
  *(ushort4*)(dst + i) = o;
}

// ---------------- qkv GEMM: 128x128 tile, C = A @ B^T + bias ----------------
// R13 = R7 body (bf16 async-DMA both sides — fused-fp32-A abandoned after
// R8-R12: best fused 227 vs split 221.7) + R11-PROVEN XCD-panel swizzle:
// 1D grid 768, the 8 n-blocks sharing an A-panel all have bid&7 == xcd ->
// same XCD-L2 -> panel fetched once (R11 A/B: FETCH 200->49MB).
// z==0 scaled by QSCALE; z==2 writes VT layout [b][h][kt64][d][k].
__global__ __launch_bounds__(256, 3) void qkv_gemm(
    const unsigned short* Xq, const unsigned short* Xk, const unsigned short* Xv,
    const unsigned short* Wq, const unsigned short* Wk, const unsigned short* Wv,
    const float* bq, const float* bk, const float* bv,
    unsigned short* Qo, unsigned short* Ko, unsigned short* VTo) {
  __shared__ unsigned short As[128 * 64], Bs[128 * 64];

  const int bid  = blockIdx.x;
  const int xcd  = bid & 7;
  const int idx  = bid >> 3;
  const int pgrp = idx >> 3;              // 0..11
  const int nblk = idx & 7;
  const int panel = xcd + 8 * pgrp;       // 0..95
  const int mblk = panel & 31;
  const int z    = panel >> 5;            // 0..2

  const unsigned short *A, *Bw; const float* bias; unsigned short* Cout;
  if (z == 0)      { A = Xq; Bw = Wq; bias = bq; Cout = Qo; }
  else if (z == 1) { A = Xk; Bw = Wk; bias = bk; Cout = Ko; }
  else             { A = Xv; Bw = Wv; bias = bv; Cout = VTo; }

  const int K = DM, N = DM;
  const int m0 = mblk * 128, n0 = nblk * 128;
  const int tid  = threadIdx.x;
  const int lane = tid & 63, wvi = tid >> 6;
  const int lq = lane & 15, quad = lane >> 4;
  const int wrow = wvi >> 1, wcol = wvi & 1;

  floatx4 acc[4][4];
  #pragma unroll
  for (int i = 0; i < 4; i++)
    #pragma unroll
    for (int j = 0; j < 4; j++)
      #pragma unroll
      for (int e = 0; e < 4; e++) acc[i][j][e] = 0.0f;

  for (int kt = 0; kt < K; kt += 64) {
    #pragma unroll
    for (int cc = 0; cc < 4; cc++) {
      int c = wvi + cc * 4;
      int e = c * 512 + lane * 8;
      int r = e >> 6, col = e & 63;
      async_ld16(A  + (size_t)(m0 + r) * K + kt + col, As + c * 512);
      async_ld16(Bw + (size_t)(n0 + r) * K + kt + col, Bs + c * 512);
    }
    __syncthreads();
    #pragma unroll
    for (int ks = 0; ks < 64; ks += 32) {
      short8 af[4], bf[4];
      #pragma unroll
      for (int i = 0; i < 4; i++)
        af[i] = *(const short8*)&As[(wrow * 64 + i * 16 + lq) * 64 + ks + quad * 8];
      #pragma unroll
      for (int j = 0; j < 4; j++)
        bf[j] = *(const short8*)&Bs[(wcol * 64 + j * 16 + lq) * 64 + ks + quad * 8];
      #pragma unroll
      for (int i = 0; i < 4; i++)
        #pragma unroll
        for (int j = 0; j < 4; j++)
          acc[i][j] = __builtin_amdgcn_mfma_f32_16x16x32_bf16(af[i], bf[j], acc[i][j], 0, 0, 0);
    }
    __syncthreads();
  }

  if (z == 2) {
    #pragma unroll
    for (int i = 0; i < 4; i++) {
      const int rowg = m0 + wrow * 64 + i * 16 + quad * 4;   // +r
      const int bb  = rowg >> 11;
      const int kt2 = (rowg & 2047) >> 6;
      const int k0  = rowg & 63;
      #pragma unroll
      for (int j = 0; j < 4; j++) {
        const int colg = n0 + wcol * 64 + j * 16 + lq;
        const int h2 = colg >> 6, d2 = colg & 63;
        const float bb_v = bias[colg];
        ushort4 w;
        w.x = f2bf(acc[i][j][0] + bb_v);
        w.y = f2bf(acc[i][j][1] + bb_v);
        w.z = f2bf(acc[i][j][2] + bb_v);
        w.w = f2bf(acc[i][j][3] + bb_v);
        *(ushort4*)(Cout + (size_t)((bb * HEADS + h2) * 32 + kt2) * 4096 + d2 * 64 + k0) = w;
      }
    }
  } else {
    const float oscale = (z == 0) ? QSCALE : 1.0f;
    #pragma unroll
    for (int i = 0; i < 4; i++) {
      #pragma unroll
      for (int j = 0; j < 4; j++) {
        int colg = n0 + wcol * 64 + j * 16 + lq;
        float bb = bias[colg];
        #pragma unroll
        for (int r = 0; r < 4; r++) {
          int rowg = m0 + wrow * 64 + i * 16 + quad * 4 + r;
          Cout[(size_t)rowg * N + colg] = f2bf((acc[i][j][r] + bb) * oscale);
        }
      }
    }
  }
}

// ---------------- out GEMM: 64x128 tile, fp32 out ----------------
// R13: + XCD-panel swizzle (1D grid 512): the 8 n-blocks sharing an A-panel
// (64 rows of Ob) have bid&7 == xcd -> A-panel fetched once per XCD; B (2MB)
// becomes XCD-L2-resident per slot.
__global__ __launch_bounds__(256, 4) void out_gemm(
    const unsigned short* __restrict__ A, const unsigned short* __restrict__ Bw,
    const float* __restrict__ bias, float* __restrict__ C) {
  __shared__ unsigned short As[64 * 64], Bs[128 * 64];
  const int K = DM, N = DM;

  const int bid  = blockIdx.x;
  const int xcd  = bid & 7;
  const int idx  = bid >> 3;              // 0..63
  const int pgrp = idx >> 3;              // 0..7
  const int nblk = idx & 7;
  const int mblk = xcd + 8 * pgrp;        // 0..63

  const int m0 = mblk * 64, n0 = nblk * 128;
  const int tid  = threadIdx.x;
  const int lane = tid & 63, wvi = tid >> 6;
  const int lq = lane & 15, quad = lane >> 4;

  floatx4 acc[8];
  #pragma unroll
  for (int j = 0; j < 8; j++)
    #pragma unroll
    for (int e = 0; e < 4; e++) acc[j][e] = 0.0f;

  for (int kt = 0; kt < K; kt += 64) {
    #pragma unroll
    for (int cc = 0; cc < 2; cc++) {           // A: 8 chunks of 512
      int c = wvi + cc * 4;
      int e = c * 512 + lane * 8;
      int r = e >> 6, col = e & 63;
      async_ld16(A + (size_t)(m0 + r) * K + kt + col, As + c * 512);
    }
    #pragma unroll
    for (int cc = 0; cc < 4; cc++) {           // B: 16 chunks of 512
      int c = wvi + cc * 4;
      int e = c * 512 + lane * 8;
      int r = e >> 6, col = e & 63;
      async_ld16(Bw + (size_t)(n0 + r) * K + kt + col, Bs + c * 512);
    }
    __syncthreads();
    #pragma unroll
    for (int ks = 0; ks < 64; ks += 32) {
      const short8 af = *(const short8*)&As[(wvi * 16 + lq) * 64 + ks + quad * 8];
      #pragma unroll
      for (int j = 0; j < 8; j++) {
        const short8 bf = *(const short8*)&Bs[(j * 16 + lq) * 64 + ks + quad * 8];
        acc[j] = __builtin_amdgcn_mfma_f32_16x16x32_bf16(af, bf, acc[j], 0, 0, 0);
      }
    }
    __syncthreads();
  }

  #pragma unroll
  for (int j = 0; j < 8; j++) {
    const int colg = n0 + j * 16 + lq;
    const float bb = bias[colg];
    #pragma unroll
    for (int r = 0; r < 4; r++) {
      const int rowg = m0 + wvi * 16 + quad * 4 + r;
      C[(size_t)rowg * N + colg] = acc[j][r] + bb;
    }
  }
}

// ---------------- flash attention (R7 frozen: R2 structure + setprio) ----------------
__global__ __launch_bounds__(256, 4) void attn_kernel(
    const unsigned short* __restrict__ Q, const unsigned short* __restrict__ K,
    const unsigned short* __restrict__ VT, const unsigned char* __restrict__ kpm,
    unsigned short* __restrict__ O) {
  __shared__ unsigned short Ks[64 * 72];
  __shared__ unsigned short VTs[64 * 72];
  __shared__ unsigned short Ps[4][16 * 72];

  const int bid = blockIdx.x;
  const int qt = 31 - (bid >> 5);        // longest q-tiles first
  const int bh = bid & 31;
  const int h = bh & 15, b = bh >> 4;
  const int tid = threadIdx.x, lane = tid & 63, wvi = tid >> 6;
  const int lq = lane & 15, quad = lane >> 4;
  const size_t bbase = (size_t)b * SEQL * DM;

  const int srow = tid >> 4;
  const int scol = (tid & 15) * 4;

  const unsigned short* kptr = K + bbase + (size_t)h * DH + (size_t)srow * DM + scol;
  const unsigned short* vptr = VT + (size_t)(b * HEADS + h) * 32 * 4096 + srow * 64 + scol;
  const unsigned char*  mptr = kpm + (size_t)b * SEQL + quad * 4;

  const unsigned short* Qrow = Q + bbase + (size_t)(qt * 64 + wvi * 16 + lq) * DM + h * DH;
  const short8 qf0 = *(const short8*)(Qrow + quad * 8);
  const short8 qf1 = *(const short8*)(Qrow + 32 + quad * 8);

  ushort4 kr[4], vr[4];
  unsigned int mr[4];
  #pragma unroll
  for (int j = 0; j < 4; j++) {
    kr[j] = *(const ushort4*)(kptr + (size_t)j * 16 * DM);
    vr[j] = *(const ushort4*)(vptr + j * 1024);
  }
  #pragma unroll
  for (int t = 0; t < 4; t++) mr[t] = *(const unsigned int*)(mptr + t * 16);
  kptr += (size_t)64 * DM; vptr += 4096; mptr += 64;

  floatx4 o[4];
  #pragma unroll
  for (int t = 0; t < 4; t++)
    #pragma unroll
    for (int e = 0; e < 4; e++) o[t][e] = 0.f;

  floatx4 lacc;                           // row-sum accumulator via ones-MFMA
  #pragma unroll
  for (int e = 0; e < 4; e++) lacc[e] = 0.f;

  floatx4 zf;                             // hoisted zero C-operand
  #pragma unroll
  for (int e = 0; e < 4; e++) zf[e] = 0.f;

  short8 ones8;                           // bf16 1.0 broadcast (row-sum B)
  #pragma unroll
  for (int e = 0; e < 8; e++) ones8[e] = (short)0x3F80;

  const int qg = wvi * 16 + lq;

  auto tile_body = [&](bool diag, const unsigned int* mcur) {
    floatx4 st[4];
    __builtin_amdgcn_s_setprio(1);
    #pragma unroll
    for (int t = 0; t < 4; t++) {
      const short8 a0 = *(const short8*)&Ks[(t * 16 + lq) * 72 + quad * 8];
      const short8 a1 = *(const short8*)&Ks[(t * 16 + lq) * 72 + 32 + quad * 8];
      st[t] = __builtin_amdgcn_mfma_f32_16x16x32_bf16(a0, qf0, zf, 0, 0, 0);
      st[t] = __builtin_amdgcn_mfma_f32_16x16x32_bf16(a1, qf1, st[t], 0, 0, 0);
    }
    __builtin_amdgcn_s_setprio(0);

    float x[4][4];
    #pragma unroll
    for (int t = 0; t < 4; t++)
      #pragma unroll
      for (int r = 0; r < 4; r++) x[t][r] = st[t][r];

    if (__any((int)((mcur[0] | mcur[1] | mcur[2] | mcur[3]) != 0u))) {   // rare
      #pragma unroll
      for (int t = 0; t < 4; t++)
        #pragma unroll
        for (int r = 0; r < 4; r++)
          if ((mcur[t] >> (8 * r)) & 0xffu) x[t][r] = -1e33f;
    }
    if (diag) {
      #pragma unroll
      for (int t = 0; t < 4; t++)
        #pragma unroll
        for (int r = 0; r < 4; r++)
          if (t * 16 + quad * 4 + r > qg) x[t][r] = -1e33f;
    }

    // p = exp2(S * SC)  — scale pre-folded into Q, C0 cancels in o/l
    #pragma unroll
    for (int t = 0; t < 4; t++)
      #pragma unroll
      for (int r = 0; r < 4; r++)
        x[t][r] = exp2_fast(x[t][r]);

    #pragma unroll
    for (int t = 0; t < 4; t++) {
      unsigned int p01 = cvt_pk_bf16(x[t][0], x[t][1]);
      unsigned int p23 = cvt_pk_bf16(x[t][2], x[t][3]);
      *(uint2*)&Ps[wvi][lq * 72 + t * 16 + quad * 4] = make_uint2(p01, p23);
    }

    const short8 pa0 = *(const short8*)&Ps[wvi][lq * 72 + quad * 8];
    const short8 pa1 = *(const short8*)&Ps[wvi][lq * 72 + 32 + quad * 8];
    __builtin_amdgcn_s_setprio(1);
    #pragma unroll
    for (int t = 0; t < 4; t++) {
      const short8 b0 = *(const short8*)&VTs[(t * 16 + lq) * 72 + quad * 8];
      const short8 b1 = *(const short8*)&VTs[(t * 16 + lq) * 72 + 32 + quad * 8];
      o[t] = __builtin_amdgcn_mfma_f32_16x16x32_bf16(pa0, b0, o[t], 0, 0, 0);
      o[t] = __builtin_amdgcn_mfma_f32_16x16x32_bf16(pa1, b1, o[t], 0, 0, 0);
    }
    // l += P @ ones  (row-sum on the matrix pipe; consistent with bf16 numerator)
    lacc = __builtin_amdgcn_mfma_f32_16x16x32_bf16(pa0, ones8, lacc, 0, 0, 0);
    lacc = __builtin_amdgcn_mfma_f32_16x16x32_bf16(pa1, ones8, lacc, 0, 0, 0);
    __builtin_amdgcn_s_setprio(0);
  };

  for (int kt = 0; kt < qt; kt++) {
    __syncthreads();
    #pragma unroll
    for (int j = 0; j < 4; j++) {
      *(ushort4*)&Ks [(j * 16 + srow) * 72 + scol] = kr[j];
      *(ushort4*)&VTs[(j * 16 + srow) * 72 + scol] = vr[j];
    }
    unsigned int mcur[4];
    #pragma unroll
    for (int t = 0; t < 4; t++) mcur[t] = mr[t];
    __syncthreads();

    #pragma unroll
    for (int j = 0; j < 4; j++) {
      kr[j] = *(const ushort4*)(kptr + (size_t)j * 16 * DM);
      vr[j] = *(const ushort4*)(vptr + j * 1024);
    }
    #pragma unroll
    for (int t = 0; t < 4; t++) mr[t] = *(const unsigned int*)(mptr + t * 16);
    kptr += (size_t)64 * DM; vptr += 4096; mptr += 64;

    tile_body(false, mcur);
  }

  __syncthreads();
  #pragma unroll
  for (int j = 0; j < 4; j++) {
    *(ushort4*)&Ks [(j * 16 + srow) * 72 + scol] = kr[j];
    *(ushort4*)&VTs[(j * 16 + srow) * 72 + scol] = vr[j];
  }
  __syncthreads();
  tile_body(true, mr);

  // lacc[r] holds l for q-row (wvi*16 + quad*4 + r), replicated across lq
  float linv[4];
  #pragma unroll
  for (int r = 0; r < 4; r++) linv[r] = 1.0f / lacc[r];
  #pragma unroll
  for (int t = 0; t < 4; t++)
    #pragma unroll
    for (int r = 0; r < 4; r++) {
      const int rowg = qt * 64 + wvi * 16 + quad * 4 + r;
      const int colg = h * 64 + t * 16 + lq;
      O[bbase + (size_t)rowg * DM + colg] = f2bf(o[t][r] * linv[r]);
    }
}

// ---------------- launch ----------------
extern "C" void kernel_launch(void* const* d_in, const int* in_sizes, int n_in,
                              void* d_out, int out_size, void* d_ws, size_t ws_size,
                              hipStream_t stream) {
  const float* qin = (const float*)d_in[0];
  const float* kin = (const float*)d_in[1];
  const float* vin = (const float*)d_in[2];
  const unsigned char* kpm = (const unsigned char*)d_in[3];
  const float* wq = (const float*)d_in[4];
  const float* bq = (const float*)d_in[5];
  const float* wk = (const float*)d_in[6];
  const float* bk = (const float*)d_in[7];
  const float* wv = (const float*)d_in[8];
  const float* bv = (const float*)d_in[9];
  const float* wo = (const float*)d_in[10];
  const float* bo = (const float*)d_in[11];

  const size_t XN = (size_t)MTOT * DM;   // 4,194,304
  const size_t WN = (size_t)DM * DM;     // 1,048,576
  unsigned short* Xq  = (unsigned short*)d_ws;
  unsigned short* Xk  = Xq  + XN;
  unsigned short* Xv  = Xk  + XN;
  unsigned short* Wqb = Xv  + XN;
  unsigned short* Wkb = Wqb + WN;
  unsigned short* Wvb = Wkb + WN;
  unsigned short* Wob = Wvb + WN;
  unsigned short* Qb  = Wob + WN;
  unsigned short* Kb  = Qb  + XN;
  unsigned short* VTg = Kb  + XN;   // V written directly in VT layout by qkv_gemm
  unsigned short* Ob  = VTg + XN;   // total 64 MiB

  cvt_all<<<dim3(16384), 256, 0, stream>>>(qin, kin, vin, wq, wk, wv, wo,
                                           Xq, Xk, Xv, Wqb, Wkb, Wvb, Wob);

  qkv_gemm<<<dim3(768), 256, 0, stream>>>(Xq, Xk, Xv, Wqb, Wkb, Wvb, bq, bk, bv, Qb, Kb, VTg);

  attn_kernel<<<dim3(BATCH * HEADS * (SEQL / 64)), 256, 0, stream>>>(Qb, Kb, VTg, kpm, Ob);

  out_gemm<<<dim3(512), 256, 0, stream>>>(Ob, Wob, bo, (float*)d_out);
}

// Round 14
// 218.095 us; speedup vs baseline: 1.1903x; 1.0065x over previous
//
#include <hip/hip_runtime.h>
#include <cstdint>
#include <cstddef>

#define DM   1024
#define HEADS 16
#define DH    64
#define SEQL  2048
#define BATCH 2
#define MTOT  (BATCH*SEQL)   // 4096

typedef __attribute__((ext_vector_type(8))) short short8;
typedef __attribute__((ext_vector_type(4))) float floatx4;

__device__ __forceinline__ unsigned short f2bf(float f) {
  unsigned int u = __float_as_uint(f);
  u = (u + 0x7FFFu + ((u >> 16) & 1u)) >> 16;   // RNE
  return (unsigned short)u;
}

__device__ __forceinline__ float exp2_fast(float x) {
#if __has_builtin(__builtin_amdgcn_exp2f)
  return __builtin_amdgcn_exp2f(x);      // single v_exp_f32
#else
  return exp2f(x);
#endif
}

__device__ __forceinline__ unsigned int cvt_pk_bf16(float lo, float hi) {
  unsigned int r;
  asm("v_cvt_pk_bf16_f32 %0, %1, %2" : "=v"(r) : "v"(lo), "v"(hi));
  return r;
}

__device__ __forceinline__ void async_ld16(const void* g, void* l) {
  __builtin_amdgcn_global_load_lds(
      (const __attribute__((address_space(1))) unsigned int*)g,
      (__attribute__((address_space(3))) unsigned int*)l, 16, 0, 0);
}

// 1/sqrt(64) * log2(e) — folded into Q at qkv_gemm epilogue
#define QSCALE 0.1803368801111204f

// ---------------- fused fp32->bf16 convert (7 tensors) ----------------
__global__ void cvt_all(const float* __restrict__ q, const float* __restrict__ k,
                        const float* __restrict__ v, const float* __restrict__ w0,
                        const float* __restrict__ w1, const float* __restrict__ w2,
                        const float* __restrict__ w3,
                        unsigned short* __restrict__ Xq, unsigned short* __restrict__ Xk,
                        unsigned short* __restrict__ Xv, unsigned short* __restrict__ W0,
                        unsigned short* __restrict__ W1, unsigned short* __restrict__ W2,
                        unsigned short* __restrict__ W3) {
  const int bid = blockIdx.x;
  const float* src; unsigned short* dst; int base;
  if (bid < 12288) {
    int seg = bid >> 12;
    base = (bid & 4095) * 1024;
    src = seg == 0 ? q : seg == 1 ? k : v;
    dst = seg == 0 ? Xq : seg == 1 ? Xk : Xv;
  } else {
    int b2 = bid - 12288;
    int seg = b2 >> 10;
    base = (b2 & 1023) * 1024;
    src = seg == 0 ? w0 : seg == 1 ? w1 : seg == 2 ? w2 : w3;
    dst = seg == 0 ? W0 : seg == 1 ? W1 : seg == 2 ? W2 : W3;
  }
  int i = base + threadIdx.x * 4;
  float4 vv = *(const float4*)(src + i);
  ushort4 o;
  o.x = f2bf(vv.x); o.y = f2bf(vv.y); o.z = f2bf(vv.z); o.w = f2bf(vv.w);
  *(ushort4*)(dst + i) = o;
}

// ---------------- qkv GEMM: 128x128 tile + XCD-panel swizzle (R13-proven) ----------------
__global__ __launch_bounds__(256, 3) void qkv_gemm(
    const unsigned short* Xq, const unsigned short* Xk, const unsigned short* Xv,
    const unsigned short* Wq, const unsigned short* Wk, const unsigned short* Wv,
    const float* bq, const float* bk, const float* bv,
    unsigned short* Qo, unsigned short* Ko, unsigned short* VTo) {
  __shared__ unsigned short As[128 * 64], Bs[128 * 64];

  const int bid  = blockIdx.x;
  const int xcd  = bid & 7;
  const int idx  = bid >> 3;
  const int pgrp = idx >> 3;              // 0..11
  const int nblk = idx & 7;
  const int panel = xcd + 8 * pgrp;       // 0..95
  const int mblk = panel & 31;
  const int z    = panel >> 5;            // 0..2

  const unsigned short *A, *Bw; const float* bias; unsigned short* Cout;
  if (z == 0)      { A = Xq; Bw = Wq; bias = bq; Cout = Qo; }
  else if (z == 1) { A = Xk; Bw = Wk; bias = bk; Cout = Ko; }
  else             { A = Xv; Bw = Wv; bias = bv; Cout = VTo; }

  const int K = DM, N = DM;
  const int m0 = mblk * 128, n0 = nblk * 128;
  const int tid  = threadIdx.x;
  const int lane = tid & 63, wvi = tid >> 6;
  const int lq = lane & 15, quad = lane >> 4;
  const int wrow = wvi >> 1, wcol = wvi & 1;

  floatx4 acc[4][4];
  #pragma unroll
  for (int i = 0; i < 4; i++)
    #pragma unroll
    for (int j = 0; j < 4; j++)
      #pragma unroll
      for (int e = 0; e < 4; e++) acc[i][j][e] = 0.0f;

  for (int kt = 0; kt < K; kt += 64) {
    #pragma unroll
    for (int cc = 0; cc < 4; cc++) {
      int c = wvi + cc * 4;
      int e = c * 512 + lane * 8;
      int r = e >> 6, col = e & 63;
      async_ld16(A  + (size_t)(m0 + r) * K + kt + col, As + c * 512);
      async_ld16(Bw + (size_t)(n0 + r) * K + kt + col, Bs + c * 512);
    }
    __syncthreads();
    #pragma unroll
    for (int ks = 0; ks < 64; ks += 32) {
      short8 af[4], bf[4];
      #pragma unroll
      for (int i = 0; i < 4; i++)
        af[i] = *(const short8*)&As[(wrow * 64 + i * 16 + lq) * 64 + ks + quad * 8];
      #pragma unroll
      for (int j = 0; j < 4; j++)
        bf[j] = *(const short8*)&Bs[(wcol * 64 + j * 16 + lq) * 64 + ks + quad * 8];
      #pragma unroll
      for (int i = 0; i < 4; i++)
        #pragma unroll
        for (int j = 0; j < 4; j++)
          acc[i][j] = __builtin_amdgcn_mfma_f32_16x16x32_bf16(af[i], bf[j], acc[i][j], 0, 0, 0);
    }
    __syncthreads();
  }

  if (z == 2) {
    #pragma unroll
    for (int i = 0; i < 4; i++) {
      const int rowg = m0 + wrow * 64 + i * 16 + quad * 4;   // +r
      const int bb  = rowg >> 11;
      const int kt2 = (rowg & 2047) >> 6;
      const int k0  = rowg & 63;
      #pragma unroll
      for (int j = 0; j < 4; j++) {
        const int colg = n0 + wcol * 64 + j * 16 + lq;
        const int h2 = colg >> 6, d2 = colg & 63;
        const float bb_v = bias[colg];
        ushort4 w;
        w.x = f2bf(acc[i][j][0] + bb_v);
        w.y = f2bf(acc[i][j][1] + bb_v);
        w.z = f2bf(acc[i][j][2] + bb_v);
        w.w = f2bf(acc[i][j][3] + bb_v);
        *(ushort4*)(Cout + (size_t)((bb * HEADS + h2) * 32 + kt2) * 4096 + d2 * 64 + k0) = w;
      }
    }
  } else {
    const float oscale = (z == 0) ? QSCALE : 1.0f;
    #pragma unroll
    for (int i = 0; i < 4; i++) {
      #pragma unroll
      for (int j = 0; j < 4; j++) {
        int colg = n0 + wcol * 64 + j * 16 + lq;
        float bb = bias[colg];
        #pragma unroll
        for (int r = 0; r < 4; r++) {
          int rowg = m0 + wrow * 64 + i * 16 + quad * 4 + r;
          Cout[(size_t)rowg * N + colg] = f2bf((acc[i][j][r] + bb) * oscale);
        }
      }
    }
  }
}

// ---------------- out GEMM: 64x128 tile + XCD-panel swizzle (R13-proven) ----------------
__global__ __launch_bounds__(256, 4) void out_gemm(
    const unsigned short* __restrict__ A, const unsigned short* __restrict__ Bw,
    const float* __restrict__ bias, float* __restrict__ C) {
  __shared__ unsigned short As[64 * 64], Bs[128 * 64];
  const int K = DM, N = DM;

  const int bid  = blockIdx.x;
  const int xcd  = bid & 7;
  const int idx  = bid >> 3;              // 0..63
  const int pgrp = idx >> 3;              // 0..7
  const int nblk = idx & 7;
  const int mblk = xcd + 8 * pgrp;        // 0..63

  const int m0 = mblk * 64, n0 = nblk * 128;
  const int tid  = threadIdx.x;
  const int lane = tid & 63, wvi = tid >> 6;
  const int lq = lane & 15, quad = lane >> 4;

  floatx4 acc[8];
  #pragma unroll
  for (int j = 0; j < 8; j++)
    #pragma unroll
    for (int e = 0; e < 4; e++) acc[j][e] = 0.0f;

  for (int kt = 0; kt < K; kt += 64) {
    #pragma unroll
    for (int cc = 0; cc < 2; cc++) {           // A: 8 chunks of 512
      int c = wvi + cc * 4;
      int e = c * 512 + lane * 8;
      int r = e >> 6, col = e & 63;
      async_ld16(A + (size_t)(m0 + r) * K + kt + col, As + c * 512);
    }
    #pragma unroll
    for (int cc = 0; cc < 4; cc++) {           // B: 16 chunks of 512
      int c = wvi + cc * 4;
      int e = c * 512 + lane * 8;
      int r = e >> 6, col = e & 63;
      async_ld16(Bw + (size_t)(n0 + r) * K + kt + col, Bs + c * 512);
    }
    __syncthreads();
    #pragma unroll
    for (int ks = 0; ks < 64; ks += 32) {
      const short8 af = *(const short8*)&As[(wvi * 16 + lq) * 64 + ks + quad * 8];
      #pragma unroll
      for (int j = 0; j < 8; j++) {
        const short8 bf = *(const short8*)&Bs[(j * 16 + lq) * 64 + ks + quad * 8];
        acc[j] = __builtin_amdgcn_mfma_f32_16x16x32_bf16(af, bf, acc[j], 0, 0, 0);
      }
    }
    __syncthreads();
  }

  #pragma unroll
  for (int j = 0; j < 8; j++) {
    const int colg = n0 + j * 16 + lq;
    const float bb = bias[colg];
    #pragma unroll
    for (int r = 0; r < 4; r++) {
      const int rowg = m0 + wvi * 16 + quad * 4 + r;
      C[(size_t)rowg * N + colg] = acc[j][r] + bb;
    }
  }
}

// ---------------- flash attention ----------------
// R14: KVBLK 64->128. Same proven R2 structure (LDS-staged K+V, 2 barriers
// per chain, reg prefetch), but each chain stages a 128-row K/V tile and runs
// the 64-wide tile body TWICE (h=0,1) between the same barrier pair.
// Chains/block halve (mean 16.5 -> 8.7) — attacks the serial-chain count,
// which R3 (LDS traffic), R4/R5 (staging removal) and R7 (setprio) did not.
// st/x/Ps reused across halves -> VGPR stays ~90 (kr/vr prefetch doubles).
// LDS 45KB -> 3 blocks/CU (the one cost: 16->12 waves/CU).
// Bounds: last-chain 128-row reads stay inside K/VT/kpm for all qt; the
// odd-half skip is block-uniform (qt is per-block).
__global__ __launch_bounds__(256, 3) void attn_kernel(
    const unsigned short* __restrict__ Q, const unsigned short* __restrict__ K,
    const unsigned short* __restrict__ VT, const unsigned char* __restrict__ kpm,
    unsigned short* __restrict__ O) {
  __shared__ unsigned short Ks[128 * 72];
  __shared__ unsigned short VTs[128 * 72];
  __shared__ unsigned short Ps[4][16 * 72];

  const int bid = blockIdx.x;
  const int qt = 31 - (bid >> 5);        // longest q-tiles first
  const int bh = bid & 31;               // bid&7 -> all q-tiles of a bh share an XCD
  const int h = bh & 15, b = bh >> 4;
  const int tid = threadIdx.x, lane = tid & 63, wvi = tid >> 6;
  const int lq = lane & 15, quad = lane >> 4;
  const size_t bbase = (size_t)b * SEQL * DM;

  const int srow = tid >> 4;
  const int scol = (tid & 15) * 4;

  const unsigned short* kptr = K + bbase + (size_t)h * DH + (size_t)srow * DM + scol;
  const unsigned short* vptr = VT + (size_t)(b * HEADS + h) * 32 * 4096 + srow * 64 + scol;
  const unsigned char*  mptr = kpm + (size_t)b * SEQL + quad * 4;

  const unsigned short* Qrow = Q + bbase + (size_t)(qt * 64 + wvi * 16 + lq) * DM + h * DH;
  const short8 qf0 = *(const short8*)(Qrow + quad * 8);
  const short8 qf1 = *(const short8*)(Qrow + 32 + quad * 8);

  const int nc = (qt + 2) >> 1;          // 128-row chains covering k<=qt*64+63

  // prologue: prefetch chain 0 (rows 0..127 — in-bounds for all qt)
  ushort4 kr[8], vr[8];
  unsigned int mr[8];
  #pragma unroll
  for (int j = 0; j < 8; j++) {
    kr[j] = *(const ushort4*)(kptr + (size_t)j * 16 * DM);
    vr[j] = *(const ushort4*)(vptr + j * 1024);
  }
  #pragma unroll
  for (int t = 0; t < 8; t++) mr[t] = *(const unsigned int*)(mptr + t * 16);
  kptr += (size_t)128 * DM; vptr += 8192; mptr += 128;

  floatx4 o[4];
  #pragma unroll
  for (int t = 0; t < 4; t++)
    #pragma unroll
    for (int e = 0; e < 4; e++) o[t][e] = 0.f;

  floatx4 lacc;                           // row-sum accumulator via ones-MFMA
  #pragma unroll
  for (int e = 0; e < 4; e++) lacc[e] = 0.f;

  floatx4 zf;                             // hoisted zero C-operand
  #pragma unroll
  for (int e = 0; e < 4; e++) zf[e] = 0.f;

  short8 ones8;                           // bf16 1.0 broadcast (row-sum B)
  #pragma unroll
  for (int e = 0; e < 8; e++) ones8[e] = (short)0x3F80;

  const int qg = wvi * 16 + lq;

  // 64-wide tile body at LDS row offset hh*64; mcur points at 4 mask words
  auto tile_body = [&](int hh, bool diag, const unsigned int* mcur) {
    const int ro = hh * 64;
    floatx4 st[4];
    __builtin_amdgcn_s_setprio(1);
    #pragma unroll
    for (int t = 0; t < 4; t++) {
      const short8 a0 = *(const short8*)&Ks[(ro + t * 16 + lq) * 72 + quad * 8];
      const short8 a1 = *(const short8*)&Ks[(ro + t * 16 + lq) * 72 + 32 + quad * 8];
      st[t] = __builtin_amdgcn_mfma_f32_16x16x32_bf16(a0, qf0, zf, 0, 0, 0);
      st[t] = __builtin_amdgcn_mfma_f32_16x16x32_bf16(a1, qf1, st[t], 0, 0, 0);
    }
    __builtin_amdgcn_s_setprio(0);

    float x[4][4];
    #pragma unroll
    for (int t = 0; t < 4; t++)
      #pragma unroll
      for (int r = 0; r < 4; r++) x[t][r] = st[t][r];

    if (__any((int)((mcur[0] | mcur[1] | mcur[2] | mcur[3]) != 0u))) {   // rare
      #pragma unroll
      for (int t = 0; t < 4; t++)
        #pragma unroll
        for (int r = 0; r < 4; r++)
          if ((mcur[t] >> (8 * r)) & 0xffu) x[t][r] = -1e33f;
    }
    if (diag) {
      #pragma unroll
      for (int t = 0; t < 4; t++)
        #pragma unroll
        for (int r = 0; r < 4; r++)
          if (t * 16 + quad * 4 + r > qg) x[t][r] = -1e33f;
    }

    // p = exp2(S * SC)  — scale pre-folded into Q, C0 cancels in o/l
    #pragma unroll
    for (int t = 0; t < 4; t++)
      #pragma unroll
      for (int r = 0; r < 4; r++)
        x[t][r] = exp2_fast(x[t][r]);

    #pragma unroll
    for (int t = 0; t < 4; t++) {
      unsigned int p01 = cvt_pk_bf16(x[t][0], x[t][1]);
      unsigned int p23 = cvt_pk_bf16(x[t][2], x[t][3]);
      *(uint2*)&Ps[wvi][lq * 72 + t * 16 + quad * 4] = make_uint2(p01, p23);
    }

    const short8 pa0 = *(const short8*)&Ps[wvi][lq * 72 + quad * 8];
    const short8 pa1 = *(const short8*)&Ps[wvi][lq * 72 + 32 + quad * 8];
    __builtin_amdgcn_s_setprio(1);
    #pragma unroll
    for (int t = 0; t < 4; t++) {
      const short8 b0 = *(const short8*)&VTs[(ro + t * 16 + lq) * 72 + quad * 8];
      const short8 b1 = *(const short8*)&VTs[(ro + t * 16 + lq) * 72 + 32 + quad * 8];
      o[t] = __builtin_amdgcn_mfma_f32_16x16x32_bf16(pa0, b0, o[t], 0, 0, 0);
      o[t] = __builtin_amdgcn_mfma_f32_16x16x32_bf16(pa1, b1, o[t], 0, 0, 0);
    }
    // l += P @ ones  (row-sum on the matrix pipe)
    lacc = __builtin_amdgcn_mfma_f32_16x16x32_bf16(pa0, ones8, lacc, 0, 0, 0);
    lacc = __builtin_amdgcn_mfma_f32_16x16x32_bf16(pa1, ones8, lacc, 0, 0, 0);
    __builtin_amdgcn_s_setprio(0);
  };

  for (int c = 0; c < nc; c++) {
    __syncthreads();                      // prior bodies done with Ks/VTs
    #pragma unroll
    for (int j = 0; j < 8; j++) {
      *(ushort4*)&Ks [(j * 16 + srow) * 72 + scol] = kr[j];
      *(ushort4*)&VTs[(j * 16 + srow) * 72 + scol] = vr[j];
    }
    unsigned int mcur[8];
    #pragma unroll
    for (int t = 0; t < 8; t++) mcur[t] = mr[t];
    __syncthreads();                      // staged tile visible

    if (c + 1 < nc) {                     // prefetch next chain under compute
      #pragma unroll
      for (int j = 0; j < 8; j++) {
        kr[j] = *(const ushort4*)(kptr + (size_t)j * 16 * DM);
        vr[j] = *(const ushort4*)(vptr + j * 1024);
      }
      #pragma unroll
      for (int t = 0; t < 8; t++) mr[t] = *(const unsigned int*)(mptr + t * 16);
      kptr += (size_t)128 * DM; vptr += 8192; mptr += 128;
    }

    const int k0 = 2 * c;                 // first 64-tile of this chain
    tile_body(0, k0 == qt, &mcur[0]);
    if (k0 + 1 <= qt)                     // block-uniform skip (qt even, last chain)
      tile_body(1, k0 + 1 == qt, &mcur[4]);
  }

  // lacc[r] holds l for q-row (wvi*16 + quad*4 + r), replicated across lq
  float linv[4];
  #pragma unroll
  for (int r = 0; r < 4; r++) linv[r] = 1.0f / lacc[r];
  #pragma unroll
  for (int t = 0; t < 4; t++)
    #pragma unroll
    for (int r = 0; r < 4; r++) {
      const int rowg = qt * 64 + wvi * 16 + quad * 4 + r;
      const int colg = h * 64 + t * 16 + lq;
      O[bbase + (size_t)rowg * DM + colg] = f2bf(o[t][r] * linv[r]);
    }
}

// ---------------- launch ----------------
extern "C" void kernel_launch(void* const* d_in, const int* in_sizes, int n_in,
                              void* d_out, int out_size, void* d_ws, size_t ws_size,
                              hipStream_t stream) {
  const float* qin = (const float*)d_in[0];
  const float* kin = (const float*)d_in[1];
  const float* vin = (const float*)d_in[2];
  const unsigned char* kpm = (const unsigned char*)d_in[3];
  const float* wq = (const float*)d_in[4];
  const float* bq = (const float*)d_in[5];
  const float* wk = (const float*)d_in[6];
  const float* bk = (const float*)d_in[7];
  const float* wv = (const float*)d_in[8];
  const float* bv = (const float*)d_in[9];
  const float* wo = (const float*)d_in[10];
  const float* bo = (const float*)d_in[11];

  const size_t XN = (size_t)MTOT * DM;   // 4,194,304
  const size_t WN = (size_t)DM * DM;     // 1,048,576
  unsigned short* Xq  = (unsigned short*)d_ws;
  unsigned short* Xk  = Xq  + XN;
  unsigned short* Xv  = Xk  + XN;
  unsigned short* Wqb = Xv  + XN;
  unsigned short* Wkb = Wqb + WN;
  unsigned short* Wvb = Wkb + WN;
  unsigned short* Wob = Wvb + WN;
  unsigned short* Qb  = Wob + WN;
  unsigned short* Kb  = Qb  + XN;
  unsigned short* VTg = Kb  + XN;   // V written directly in VT layout by qkv_gemm
  unsigned short* Ob  = VTg + XN;   // total 64 MiB

  cvt_all<<<dim3(16384), 256, 0, stream>>>(qin, kin, vin, wq, wk, wv, wo,
                                           Xq, Xk, Xv, Wqb, Wkb, Wvb, Wob);

  qkv_gemm<<<dim3(768), 256, 0, stream>>>(Xq, Xk, Xv, Wqb, Wkb, Wvb, bq, bk, bv, Qb, Kb, VTg);

  attn_kernel<<<dim3(BATCH * HEADS * (SEQL / 64)), 256, 0, stream>>>(Qb, Kb, VTg, kpm, Ob);

  out_gemm<<<dim3(512), 256, 0, stream>>>(Ob, Wob, bo, (float*)d_out);
}